// Round 2
// baseline (1832.715 us; speedup 1.0000x reference)
//
#include <hip/hip_runtime.h>

// Problem constants (from reference)
#define B_      4
#define N_ATOMS 100000
#define D_      64
#define F_      8
#define G_      20000
#define A_      3
#define H_      16
#define AD_     (A_ * D_)                 // 192
#define BLOCK   256
#define GPB     64                         // cliques (g) per block
#define BSTRIDE ((size_t)N_ATOMS * D_)    // floats per batch slice

// 16 FMAs: one x value against one W1 row (16 outputs) held in 4 float4s.
#define FMA16(x1, wr)                                            \
    {                                                            \
        const float4 w0 = (wr)[0], w1v = (wr)[1],                \
                     w2v = (wr)[2], w3v = (wr)[3];               \
        h[0]  = fmaf((x1), w0.x,  h[0]);                         \
        h[1]  = fmaf((x1), w0.y,  h[1]);                         \
        h[2]  = fmaf((x1), w0.z,  h[2]);                         \
        h[3]  = fmaf((x1), w0.w,  h[3]);                         \
        h[4]  = fmaf((x1), w1v.x, h[4]);                         \
        h[5]  = fmaf((x1), w1v.y, h[5]);                         \
        h[6]  = fmaf((x1), w1v.z, h[6]);                         \
        h[7]  = fmaf((x1), w1v.w, h[7]);                         \
        h[8]  = fmaf((x1), w2v.x, h[8]);                         \
        h[9]  = fmaf((x1), w2v.y, h[9]);                         \
        h[10] = fmaf((x1), w2v.z, h[10]);                        \
        h[11] = fmaf((x1), w2v.w, h[11]);                        \
        h[12] = fmaf((x1), w3v.x, h[12]);                        \
        h[13] = fmaf((x1), w3v.y, h[13]);                        \
        h[14] = fmaf((x1), w3v.z, h[14]);                        \
        h[15] = fmaf((x1), w3v.w, h[15]);                        \
    }

// Consume one 32-float half-row segment (8 float4) held in `buf`.
// kbase = segment_index * 32 (runtime-uniform; LDS addr arithmetic only).
#define COMPUTE_SEG(buf, kbase)                                              \
    {                                                                        \
        _Pragma("unroll")                                                    \
        for (int k4 = 0; k4 < 8; ++k4) {                                     \
            const float4 xv = (buf)[k4];                                     \
            const float4* wr =                                               \
                (const float4*)&w1s[((kbase) + k4 * 4) * H_];                \
            FMA16(xv.x, wr + 0);                                             \
            FMA16(xv.y, wr + 4);                                             \
            FMA16(xv.z, wr + 8);                                             \
            FMA16(xv.w, wr + 12);                                            \
        }                                                                    \
    }

// One thread = one (b, f, g). Block = one f, 64 consecutive g x 4 batches
// (wave w handles batch w => coalesced index loads and output stores).
// Atom rows are read as 2 half-rows of 8 contiguous dwordx4 each (full
// 64B-line consumption), double-buffered so loads hide under 512 FMAs.
__global__ __launch_bounds__(BLOCK, 4)
void cliques_mlp_kernel(const float* __restrict__ atoms,   // [B, N_ATOMS, D]
                        const int*   __restrict__ gi,      // [F,G,A] i32/i64 (detected)
                        const float* __restrict__ W1,      // [F, AD, H]
                        const float* __restrict__ b1,      // [F, H]
                        const float* __restrict__ W2,      // [F, H, 1]
                        const float* __restrict__ b2,      // [F, 1]
                        float* __restrict__ out)           // [B, F*G]
{
    __shared__ __align__(16) float w1s[AD_ * H_];   // 12 KiB
    __shared__ float b1s[H_];
    __shared__ float w2s[H_];
    __shared__ float b2s_s;
    __shared__ int   is64_s;

    const int f   = blockIdx.y;
    const int tid = threadIdx.x;

    // ---- stage per-formula weights into LDS (coalesced float4) ----
    {
        const float4* src = (const float4*)(W1 + (size_t)f * AD_ * H_);
        float4*       dst = (float4*)w1s;
        #pragma unroll
        for (int i = 0; i < (AD_ * H_) / 4; i += BLOCK)
            dst[i + tid] = src[i + tid];
    }
    if (tid < H_) {
        b1s[tid] = b1[f * H_ + tid];
        w2s[tid] = W2[f * H_ + tid];
    }
    if (tid == 0) {
        b2s_s = b2[f];
        // int64-vs-int32: indices < 1e5 => if buffer is int64 every odd
        // 32-bit word is 0. For int32 data P(32 random idx all 0) ~ 1e-160.
        unsigned ored = 0u;
        const unsigned* u = (const unsigned*)gi;
        #pragma unroll
        for (int i = 0; i < 32; ++i) ored |= u[2 * i + 1];
        is64_s = (ored == 0u) ? 1 : 0;
    }
    __syncthreads();

    const int lane = tid & 63;   // g within block
    const int b    = tid >> 6;   // batch = wave id
    const int g    = blockIdx.x * GPB + lane;
    if (g >= G_) return;

    // ---- 3 atom indices for this clique (coalesced across the wave) ----
    const long long eidx = ((long long)f * G_ + g) * A_;
    int i0, i1, i2;
    if (is64_s) {
        i0 = gi[2 * (eidx + 0)];
        i1 = gi[2 * (eidx + 1)];
        i2 = gi[2 * (eidx + 2)];
    } else {
        i0 = gi[eidx + 0];
        i1 = gi[eidx + 1];
        i2 = gi[eidx + 2];
    }

    const float* base = atoms + (size_t)b * BSTRIDE;
    const float4* rp0 = (const float4*)(base + (size_t)i0 * D_);
    const float4* rp1 = (const float4*)(base + (size_t)i1 * D_);
    const float4* rp2 = (const float4*)(base + (size_t)i2 * D_);

    float h[H_];
    #pragma unroll
    for (int j = 0; j < H_; ++j) h[j] = b1s[j];

    // ---- 6 half-row segments (a=s>>1, half=s&1), double-buffered ----
    float4 xa[8], xb[8];
    #pragma unroll
    for (int i = 0; i < 8; ++i) xa[i] = rp0[i];   // segment 0

    #pragma unroll 1
    for (int sp = 0; sp < 3; ++sp) {
        // prefetch odd segment s1 = 2*sp+1 into xb (second half of row sp)
        {
            const float4* pn = (sp == 0) ? rp0 : (sp == 1) ? rp1 : rp2;
            pn += 8;
            #pragma unroll
            for (int i = 0; i < 8; ++i) xb[i] = pn[i];
        }
        // compute even segment 2*sp from xa
        COMPUTE_SEG(xa, (2 * sp) * 32);

        // prefetch even segment 2*sp+2 into xa (first half of row sp+1)
        if (sp < 2) {
            const float4* pn = (sp == 0) ? rp1 : rp2;
            #pragma unroll
            for (int i = 0; i < 8; ++i) xa[i] = pn[i];
        }
        // compute odd segment 2*sp+1 from xb
        COMPUTE_SEG(xb, (2 * sp + 1) * 32);
    }

    // ---- epilogue: sigmoid -> layer 2 -> sigmoid -> coalesced store ----
    float o = b2s_s;
    #pragma unroll
    for (int j = 0; j < H_; ++j) {
        const float s = 1.0f / (1.0f + __expf(-h[j]));
        o = fmaf(s, w2s[j], o);
    }
    o = 1.0f / (1.0f + __expf(-o));
    out[(size_t)b * (F_ * G_) + (size_t)f * G_ + g] = o;
}

extern "C" void kernel_launch(void* const* d_in, const int* in_sizes, int n_in,
                              void* d_out, int out_size, void* d_ws, size_t ws_size,
                              hipStream_t stream) {
    const float* atoms = (const float*)d_in[0];
    const int*   gi    = (const int*)d_in[1];
    const float* W1    = (const float*)d_in[2];
    const float* b1    = (const float*)d_in[3];
    const float* W2    = (const float*)d_in[4];
    const float* b2    = (const float*)d_in[5];
    float*       out   = (float*)d_out;

    dim3 grid((G_ + GPB - 1) / GPB, F_);
    cliques_mlp_kernel<<<grid, dim3(BLOCK), 0, stream>>>(atoms, gi, W1, b1, W2, b2, out);
}

// Round 5
// 260.858 us; speedup vs baseline: 7.0257x; 7.0257x over previous
//
#include <hip/hip_runtime.h>

// Problem constants (from reference)
#define B_      4
#define N_ATOMS 100000
#define D_      64
#define F_      8
#define G_      20000
#define A_      3
#define H_      16
#define AD_     (A_ * D_)                 // 192
#define BLOCK   256
#define GPB     64                         // cliques (g) per block
#define BSTRIDE ((size_t)N_ATOMS * D_)    // floats per batch slice

// 16 FMAs: one x value against one W1 row (16 outputs) held in 4 float4s.
#define FMA16(x1, wr)                                            \
    {                                                            \
        const float4 w0 = (wr)[0], w1v = (wr)[1],                \
                     w2v = (wr)[2], w3v = (wr)[3];               \
        h[0]  = fmaf((x1), w0.x,  h[0]);                         \
        h[1]  = fmaf((x1), w0.y,  h[1]);                         \
        h[2]  = fmaf((x1), w0.z,  h[2]);                         \
        h[3]  = fmaf((x1), w0.w,  h[3]);                         \
        h[4]  = fmaf((x1), w1v.x, h[4]);                         \
        h[5]  = fmaf((x1), w1v.y, h[5]);                         \
        h[6]  = fmaf((x1), w1v.z, h[6]);                         \
        h[7]  = fmaf((x1), w1v.w, h[7]);                         \
        h[8]  = fmaf((x1), w2v.x, h[8]);                         \
        h[9]  = fmaf((x1), w2v.y, h[9]);                         \
        h[10] = fmaf((x1), w2v.z, h[10]);                        \
        h[11] = fmaf((x1), w2v.w, h[11]);                        \
        h[12] = fmaf((x1), w3v.x, h[12]);                        \
        h[13] = fmaf((x1), w3v.y, h[13]);                        \
        h[14] = fmaf((x1), w3v.z, h[14]);                        \
        h[15] = fmaf((x1), w3v.w, h[15]);                        \
    }

// Consume one 16-float quarter-row segment (4 float4, one 64B line).
// kbase is wave-uniform (scalar) -> LDS broadcast reads, conflict-free.
#define COMPUTE_SEG4(bufv, kbase)                                            \
    {                                                                        \
        _Pragma("unroll")                                                    \
        for (int k4 = 0; k4 < 4; ++k4) {                                     \
            const float4 xv = (bufv)[k4];                                    \
            const float4* wr =                                               \
                (const float4*)&w1s[((kbase) + k4 * 4) * H_];                \
            FMA16(xv.x, wr + 0);                                             \
            FMA16(xv.y, wr + 4);                                             \
            FMA16(xv.z, wr + 8);                                             \
            FMA16(xv.w, wr + 12);                                            \
        }                                                                    \
    }

// One thread = one (b, f, g). Block = one f, 64 consecutive g x 4 batches
// (wave w handles batch w => coalesced index loads and output stores).
// Atom rows are read as 12 quarter-row segments (one full 64B line each,
// fully consumed by the owning thread => ~1x over-fetch), double-buffered
// in 2x4 float4 registers so each segment's loads hide under 256 FMAs.
// NOTE: no min-waves floor in launch_bounds — R2's (256,4) forced VGPR=64
// and spilled the buffers to scratch (4 GB of scratch writes).
__global__ __launch_bounds__(BLOCK)
void cliques_mlp_kernel(const float* __restrict__ atoms,   // [B, N_ATOMS, D]
                        const int*   __restrict__ gi,      // [F,G,A] i32/i64 (detected)
                        const float* __restrict__ W1,      // [F, AD, H]
                        const float* __restrict__ b1,      // [F, H]
                        const float* __restrict__ W2,      // [F, H, 1]
                        const float* __restrict__ b2,      // [F, 1]
                        float* __restrict__ out)           // [B, F*G]
{
    __shared__ __align__(16) float w1s[AD_ * H_];   // 12 KiB
    __shared__ float b1s[H_];
    __shared__ float w2s[H_];
    __shared__ float b2s_s;
    __shared__ int   is64_s;

    const int f   = blockIdx.y;
    const int tid = threadIdx.x;

    // ---- stage per-formula weights into LDS (coalesced float4) ----
    {
        const float4* src = (const float4*)(W1 + (size_t)f * AD_ * H_);
        float4*       dst = (float4*)w1s;
        #pragma unroll
        for (int i = 0; i < (AD_ * H_) / 4; i += BLOCK)
            dst[i + tid] = src[i + tid];
    }
    if (tid < H_) {
        b1s[tid] = b1[f * H_ + tid];
        w2s[tid] = W2[f * H_ + tid];
    }
    if (tid == 0) {
        b2s_s = b2[f];
        // int64-vs-int32: indices < 1e5 => if buffer is int64 every odd
        // 32-bit word is 0. For int32 data P(32 random idx all 0) ~ 1e-160.
        unsigned ored = 0u;
        const unsigned* u = (const unsigned*)gi;
        #pragma unroll
        for (int i = 0; i < 32; ++i) ored |= u[2 * i + 1];
        is64_s = (ored == 0u) ? 1 : 0;
    }
    __syncthreads();

    const int lane = tid & 63;   // g within block
    const int b    = tid >> 6;   // batch = wave id
    const int g    = blockIdx.x * GPB + lane;
    if (g >= G_) return;

    // ---- 3 atom indices for this clique (coalesced across the wave) ----
    const long long eidx = ((long long)f * G_ + g) * A_;
    int i0, i1, i2;
    if (is64_s) {
        i0 = gi[2 * (eidx + 0)];
        i1 = gi[2 * (eidx + 1)];
        i2 = gi[2 * (eidx + 2)];
    } else {
        i0 = gi[eidx + 0];
        i1 = gi[eidx + 1];
        i2 = gi[eidx + 2];
    }

    const float* base = atoms + (size_t)b * BSTRIDE;
    const float4* rp0 = (const float4*)(base + (size_t)i0 * D_);
    const float4* rp1 = (const float4*)(base + (size_t)i1 * D_);
    const float4* rp2 = (const float4*)(base + (size_t)i2 * D_);

    float h[H_];
    #pragma unroll
    for (int j = 0; j < H_; ++j) h[j] = b1s[j];

    // ---- 12 quarter-row segments (row = s>>2, quarter = s&3) ----
    float4 xa[4], xb[4];
    #pragma unroll
    for (int i = 0; i < 4; ++i) xa[i] = rp0[i];   // segment 0

    #pragma unroll 1
    for (int sp = 0; sp < 6; ++sp) {
        // prefetch odd segment 2*sp+1 into xb
        {
            const int so = 2 * sp + 1;
            const int ro = so >> 2, qo = so & 3;
            const float4* po = (ro == 0) ? rp0 : (ro == 1) ? rp1 : rp2;
            po += qo * 4;
            #pragma unroll
            for (int i = 0; i < 4; ++i) xb[i] = po[i];
        }
        // compute even segment 2*sp from xa (256 FMAs cover the loads)
        COMPUTE_SEG4(xa, (2 * sp) * 16);

        // prefetch even segment 2*sp+2 into xa
        if (sp < 5) {
            const int se = 2 * sp + 2;
            const int re = se >> 2, qe = se & 3;
            const float4* pe = (re == 0) ? rp0 : (re == 1) ? rp1 : rp2;
            pe += qe * 4;
            #pragma unroll
            for (int i = 0; i < 4; ++i) xa[i] = pe[i];
        }
        // compute odd segment 2*sp+1 from xb
        COMPUTE_SEG4(xb, (2 * sp + 1) * 16);
    }

    // ---- epilogue: sigmoid -> layer 2 -> sigmoid -> coalesced store ----
    float o = b2s_s;
    #pragma unroll
    for (int j = 0; j < H_; ++j) {
        const float s = 1.0f / (1.0f + __expf(-h[j]));
        o = fmaf(s, w2s[j], o);
    }
    o = 1.0f / (1.0f + __expf(-o));
    out[(size_t)b * (F_ * G_) + (size_t)f * G_ + g] = o;
}

extern "C" void kernel_launch(void* const* d_in, const int* in_sizes, int n_in,
                              void* d_out, int out_size, void* d_ws, size_t ws_size,
                              hipStream_t stream) {
    const float* atoms = (const float*)d_in[0];
    const int*   gi    = (const int*)d_in[1];
    const float* W1    = (const float*)d_in[2];
    const float* b1    = (const float*)d_in[3];
    const float* W2    = (const float*)d_in[4];
    const float* b2    = (const float*)d_in[5];
    float*       out   = (float*)d_out;

    dim3 grid((G_ + GPB - 1) / GPB, F_);
    cliques_mlp_kernel<<<grid, dim3(BLOCK), 0, stream>>>(atoms, gi, W1, b1, W2, b2, out);
}